// Round 7
// baseline (4063.170 us; speedup 1.0000x reference)
//
#include <hip/hip_runtime.h>

// GeneratorDecoder: 128-step LSTM (H=32) + gumbel-argmax head (P=7), B=32768.
// Round 7: FOUR batch elements per wave (round-6 structure, numerically
// validated) + amdgpu_waves_per_eu(2,2) so the allocator actually gets the
// 256-VGPR budget (round 6 capped itself at 128 and spilled the weight set
// to scratch every step -> 1.1 GB phantom FETCH). Gumbel noise is
// precomputed by a memory-bound prekernel into d_ws (bitwise-identical
// expression; guarded by ws_size with exact in-loop fallback), removing the
// 2 dependent logf from the per-step serial chain.

#define Hh 32
#define Pp 7
#define NDd 8

typedef float f32x2 __attribute__((ext_vector_type(2)));

static __device__ __forceinline__ f32x2 fma2(f32x2 w, float h, f32x2 a) {
  return __builtin_elementwise_fma(w, (f32x2){h, h}, a);
}

__global__ void gumbel_noise_kernel(const float4* __restrict__ u,
                                    float4* __restrict__ o, int n4) {
  int i = blockIdx.x * blockDim.x + threadIdx.x;
  int stride = gridDim.x * blockDim.x;
  for (; i < n4; i += stride) {
    float4 v = u[i];
    float4 r;
    r.x = -logf(-logf(v.x + 1e-20f) + 1e-20f);
    r.y = -logf(-logf(v.y + 1e-20f) + 1e-20f);
    r.z = -logf(-logf(v.z + 1e-20f) + 1e-20f);
    r.w = -logf(-logf(v.w + 1e-20f) + 1e-20f);
    o[i] = r;
  }
}

template <int PRE>
__global__ __launch_bounds__(64)
__attribute__((amdgpu_waves_per_eu(2, 2)))
void gen_decoder_kernel(
    const float* __restrict__ h_n, const float* __restrict__ c_n,
    const float* __restrict__ noise, const float* __restrict__ gsrc,
    const float* __restrict__ W_init, const float* __restrict__ b_init,
    const float* __restrict__ W_ih, const float* __restrict__ W_hh,
    const float* __restrict__ b_ih, const float* __restrict__ b_hh,
    const float* __restrict__ W_head, const float* __restrict__ b_head,
    float* __restrict__ out, int B, int T)
{
  __shared__ f32x2 sTIF[8 * 32];                 // [k][j] = {v(j), v(32+j)}
  __shared__ f32x2 sTGO[8 * 32];                 // [k][j] = {v(64+j), v(96+j)}
  __shared__ __align__(16) float sm_h[4 * 36];   // per-batch h, stride 36
  __shared__ __align__(16) float smL[4][56];     // 8 steps x 7 logits
  __shared__ __align__(16) float smS[4][56];     // 8 steps x 7 samples

  const int l  = threadIdx.x;      // one wave per block
  const int j  = l & 31;           // state slot
  const int gA = l >> 5;           // first owned batch (0/1)
  const int gB = gA + 2;           // second owned batch (2/3)
  const int b0 = blockIdx.x * 4;
  const int bA = b0 + gA, bB = b0 + gB;

  // fused W_ih/bias tables (wave-local, in-order: no barrier needed)
  for (int i = l; i < 8 * 32; i += 64) {
    int k = i >> 5, jj = i & 31;
    float v0 = b_ih[jj]      + b_hh[jj]      + ((k < 7) ? W_ih[jj * 7 + k]        : 0.f);
    float v1 = b_ih[32 + jj] + b_hh[32 + jj] + ((k < 7) ? W_ih[(32 + jj) * 7 + k] : 0.f);
    float v2 = b_ih[64 + jj] + b_hh[64 + jj] + ((k < 7) ? W_ih[(64 + jj) * 7 + k] : 0.f);
    float v3 = b_ih[96 + jj] + b_hh[96 + jj] + ((k < 7) ? W_ih[(96 + jj) * 7 + k] : 0.f);
    sTIF[i] = (f32x2){v0, v1};
    sTGO[i] = (f32x2){v2, v3};
  }

  // ---- h0 init for both owned batches (x dies before weight regs live) ----
  {
    float x[Hh + NDd];
#pragma unroll
    for (int i = 0; i < 8; i++)
      ((float4*)x)[i] = *(const float4*)&h_n[(size_t)bA * Hh + 4 * i];
    ((float4*)x)[8] = *(const float4*)&noise[(size_t)bA * NDd];
    ((float4*)x)[9] = *(const float4*)&noise[(size_t)bA * NDd + 4];
    float a = b_init[j];
    const float* wr = &W_init[j * (Hh + NDd)];
#pragma unroll
    for (int k = 0; k < Hh + NDd; k++) a = fmaf(wr[k], x[k], a);
    sm_h[gA * 36 + j] = a;
  }
  {
    float x[Hh + NDd];
#pragma unroll
    for (int i = 0; i < 8; i++)
      ((float4*)x)[i] = *(const float4*)&h_n[(size_t)bB * Hh + 4 * i];
    ((float4*)x)[8] = *(const float4*)&noise[(size_t)bB * NDd];
    ((float4*)x)[9] = *(const float4*)&noise[(size_t)bB * NDd + 4];
    float a = b_init[j];
    const float* wr = &W_init[j * (Hh + NDd)];
#pragma unroll
    for (int k = 0; k < Hh + NDd; k++) a = fmaf(wr[k], x[k], a);
    sm_h[gB * 36 + j] = a;
  }
  float cA = c_n[(size_t)bA * Hh + j];
  float cB = c_n[(size_t)bB * Hh + j];

  // ---- recurrent weights (slot j, rows {j,32+j,64+j,96+j}) — shared A/B ----
  f32x2 wIF[32], wGO[32];
  {
    const float* WI = W_hh + (size_t)(0 * Hh + j) * Hh;
    const float* WF = W_hh + (size_t)(1 * Hh + j) * Hh;
    const float* WG = W_hh + (size_t)(2 * Hh + j) * Hh;
    const float* WO = W_hh + (size_t)(3 * Hh + j) * Hh;
#pragma unroll
    for (int kc = 0; kc < 8; kc++) {
      float4 wi = *(const float4*)&WI[4 * kc];
      float4 wf = *(const float4*)&WF[4 * kc];
      float4 wg = *(const float4*)&WG[4 * kc];
      float4 wo = *(const float4*)&WO[4 * kc];
      wIF[4 * kc + 0] = (f32x2){wi.x, wf.x};
      wIF[4 * kc + 1] = (f32x2){wi.y, wf.y};
      wIF[4 * kc + 2] = (f32x2){wi.z, wf.z};
      wIF[4 * kc + 3] = (f32x2){wi.w, wf.w};
      wGO[4 * kc + 0] = (f32x2){wg.x, wo.x};
      wGO[4 * kc + 1] = (f32x2){wg.y, wo.y};
      wGO[4 * kc + 2] = (f32x2){wg.z, wo.z};
      wGO[4 * kc + 3] = (f32x2){wg.w, wo.w};
    }
  }

  // head weights: lane 32h+4p+q holds W_head[p][q+4m] (p<7)
  const int hp = (l & 31) >> 2;
  const int hq = l & 3;
  float whead[8];
  float bh = 0.f;
  if (hp < 7) {
#pragma unroll
    for (int m = 0; m < 8; m++) whead[m] = W_head[hp * Hh + hq + 4 * m];
    bh = b_head[hp];
  } else {
#pragma unroll
    for (int m = 0; m < 8; m++) whead[m] = 0.f;
  }

  // candidate role: group cg = l>>4 (batch), cp = l&15 (candidate, <7 active)
  const int cg  = l >> 4;
  const int cp  = l & 15;
  const int cpc = (cp < 7) ? cp : 6;
  const float* gL = gsrc + (size_t)(b0 + cg) * Pp + cpc;
  const size_t strideT = (size_t)B * Pp;
  const size_t SOFF = (size_t)B * T * Pp;   // samples block offset (floats)

  int kA = 7, kB = 7;  // y0 = 0 -> bias-only column
  float* outLA = out + (size_t)bA * T * Pp;
  float* outLB = out + (size_t)bB * T * Pp;

  for (int t = 0; t < T; ++t) {
    // gumbel noise for this step (independent of recurrence -> issue early)
    float nv;
    if constexpr (PRE) {
      nv = gL[(size_t)t * strideT];                      // precomputed
    } else {
      float uv = gL[(size_t)t * strideT];
      nv = -logf(-logf(uv + 1e-20f) + 1e-20f);           // exact same text
    }

    // gate pre-activations: two independent packed chains per lane
    f32x2 aIFA = sTIF[(kA << 5) + j], aGOA = sTGO[(kA << 5) + j];
    f32x2 aIFB = sTIF[(kB << 5) + j], aGOB = sTGO[(kB << 5) + j];
#pragma unroll
    for (int kc = 0; kc < 8; kc++) {
      float4 hvA = *(const float4*)&sm_h[gA * 36 + 4 * kc];
      float4 hvB = *(const float4*)&sm_h[gB * 36 + 4 * kc];
      aIFA = fma2(wIF[4 * kc + 0], hvA.x, aIFA);
      aGOA = fma2(wGO[4 * kc + 0], hvA.x, aGOA);
      aIFB = fma2(wIF[4 * kc + 0], hvB.x, aIFB);
      aGOB = fma2(wGO[4 * kc + 0], hvB.x, aGOB);
      aIFA = fma2(wIF[4 * kc + 1], hvA.y, aIFA);
      aGOA = fma2(wGO[4 * kc + 1], hvA.y, aGOA);
      aIFB = fma2(wIF[4 * kc + 1], hvB.y, aIFB);
      aGOB = fma2(wGO[4 * kc + 1], hvB.y, aGOB);
      aIFA = fma2(wIF[4 * kc + 2], hvA.z, aIFA);
      aGOA = fma2(wGO[4 * kc + 2], hvA.z, aGOA);
      aIFB = fma2(wIF[4 * kc + 2], hvB.z, aIFB);
      aGOB = fma2(wGO[4 * kc + 2], hvB.z, aGOB);
      aIFA = fma2(wIF[4 * kc + 3], hvA.w, aIFA);
      aGOA = fma2(wGO[4 * kc + 3], hvA.w, aGOA);
      aIFB = fma2(wIF[4 * kc + 3], hvB.w, aIFB);
      aGOB = fma2(wGO[4 * kc + 3], hvB.w, aGOB);
    }

    // cells (exact expression text of rounds 1-6), two independent chains
    float igA = 1.f / (1.f + expf(-aIFA.x));
    float fgA = 1.f / (1.f + expf(-aIFA.y));
    float ggA = tanhf(aGOA.x);
    float ogA = 1.f / (1.f + expf(-aGOA.y));
    float igB = 1.f / (1.f + expf(-aIFB.x));
    float fgB = 1.f / (1.f + expf(-aIFB.y));
    float ggB = tanhf(aGOB.x);
    float ogB = 1.f / (1.f + expf(-aGOB.y));
    float ccA = fgA * cA + igA * ggA;
    float ccB = fgB * cB + igB * ggB;
    cA = ccA;
    cB = ccB;
    float hjA = ogA * tanhf(ccA);
    float hjB = ogB * tanhf(ccB);
    sm_h[gA * 36 + j] = hjA;
    sm_h[gB * 36 + j] = hjB;

    // head: two passes (batches gA then gB), same partial/reduce shape
    float lgA = 0.f, lgB = 0.f;
    if (hp < 7) {
#pragma unroll
      for (int m = 0; m < 8; m++)
        lgA = fmaf(whead[m], sm_h[gA * 36 + hq + 4 * m], lgA);
      lgA += __shfl_xor(lgA, 1);
      lgA += __shfl_xor(lgA, 2);
      lgA += bh;
#pragma unroll
      for (int m = 0; m < 8; m++)
        lgB = fmaf(whead[m], sm_h[gB * 36 + hq + 4 * m], lgB);
      lgB += __shfl_xor(lgB, 1);
      lgB += __shfl_xor(lgB, 2);
      lgB += bh;
    }

    // fan logit (cg, cp) to candidate lane 16*cg+cp
    int srcq = 32 * (cg & 1) + 4 * cpc;
    float LrA = __shfl(lgA, srcq);   // batches 0/1
    float LrB = __shfl(lgB, srcq);   // batches 2/3
    float Lr = (cg < 2) ? LrA : LrB;

    // argmax: 8-lane lowest-index butterfly, four 16-lane groups in parallel
    float bestv = (cp < 7) ? (Lr + nv) : -__builtin_inff();
    int besti = cp;
#pragma unroll
    for (int mask = 1; mask <= 4; mask <<= 1) {
      float ov = __shfl_xor(bestv, mask);
      int   oi = __shfl_xor(besti, mask);
      if (ov > bestv || (ov == bestv && oi < besti)) { bestv = ov; besti = oi; }
    }
    kA = __shfl(besti, 16 * gA);
    kB = __shfl(besti, 16 * gB);

    // stage outputs (quad leaders p<7 write both owned batches)
    if (hp < 7 && hq == 0) {
      int t8 = (t & 7) * Pp + hp;
      smL[gA][t8] = lgA;
      smS[gA][t8] = (kA == hp) ? 1.f : 0.f;
      smL[gB][t8] = lgB;
      smS[gB][t8] = (kB == hp) ? 1.f : 0.f;
    }

    // flush every 8 steps: 14 float4 per batch, 4 batches per wave
    if ((t & 7) == 7) {
      int r = l & 31;
      if (r < 14) {
        size_t o = (size_t)(t - 7) * Pp + 4 * r;
        *(float4*)&outLA[o]        = *(const float4*)&smL[gA][4 * r];
        *(float4*)&outLA[o + SOFF] = *(const float4*)&smS[gA][4 * r];
        *(float4*)&outLB[o]        = *(const float4*)&smL[gB][4 * r];
        *(float4*)&outLB[o + SOFF] = *(const float4*)&smS[gB][4 * r];
      }
    } else if (t == T - 1) {
      int t0 = t & ~7;
      int cnt = (t - t0 + 1) * Pp;
      for (int i = l & 31; i < cnt; i += 32) {
        size_t o = (size_t)t0 * Pp + i;
        outLA[o]        = smL[gA][i];
        outLA[o + SOFF] = smS[gA][i];
        outLB[o]        = smL[gB][i];
        outLB[o + SOFF] = smS[gB][i];
      }
    }
  }
}

extern "C" void kernel_launch(void* const* d_in, const int* in_sizes, int n_in,
                              void* d_out, int out_size, void* d_ws, size_t ws_size,
                              hipStream_t stream) {
  const float* h_n     = (const float*)d_in[0];
  const float* c_n     = (const float*)d_in[1];
  const float* noise   = (const float*)d_in[2];
  const float* gumbel  = (const float*)d_in[3];
  const float* W_init  = (const float*)d_in[4];
  const float* b_init  = (const float*)d_in[5];
  const float* W_ih    = (const float*)d_in[6];
  const float* W_hh    = (const float*)d_in[7];
  const float* b_ih    = (const float*)d_in[8];
  const float* b_hh    = (const float*)d_in[9];
  const float* W_head  = (const float*)d_in[10];
  const float* b_head  = (const float*)d_in[11];

  int B = in_sizes[0] / Hh;                 // 32768
  int n = in_sizes[3];                      // T*B*P
  int T = n / (B * Pp);                     // 128
  size_t nbytes = (size_t)n * sizeof(float);
  bool pre = (ws_size >= nbytes) && (n % 4 == 0);

  if (pre) {
    gumbel_noise_kernel<<<2048, 256, 0, stream>>>(
        (const float4*)gumbel, (float4*)d_ws, n / 4);
    gen_decoder_kernel<1><<<dim3(B / 4), dim3(64), 0, stream>>>(
        h_n, c_n, noise, (const float*)d_ws, W_init, b_init, W_ih, W_hh,
        b_ih, b_hh, W_head, b_head, (float*)d_out, B, T);
  } else {
    gen_decoder_kernel<0><<<dim3(B / 4), dim3(64), 0, stream>>>(
        h_n, c_n, noise, gumbel, W_init, b_init, W_ih, W_hh,
        b_ih, b_hh, W_head, b_head, (float*)d_out, B, T);
  }
}

// Round 8
// 986.198 us; speedup vs baseline: 4.1200x; 4.1200x over previous
//
#include <hip/hip_runtime.h>

// GeneratorDecoder: 128-step LSTM (H=32) + gumbel-argmax head (P=7), B=32768.
// Round 8: two batches per wave at HALF the weight footprint. Lane l owns gate
// rows l (i|f) and l+64 (g|o) packed as f32x2 (64 weight VGPRs), and runs the
// packed chain for BOTH batches A (lanes<32 finish cell) and B (lanes>=32),
// with one shfl_xor(32) exchange per batch -> one cell per lane, no
// duplication. Live set ~105 regs < 128 -> 4 waves/SIMD (launch_bounds(64,4)).
// Gumbel noise precomputed into d_ws (exact same expression; ws-guarded
// fallback). All gate-row fmaf chains / cell text / head reduce / argmax
// butterfly / tie-break verbatim from the passing rounds 5-7 -> bit-identical.

#define Hh 32
#define Pp 7
#define NDd 8

typedef float f32x2 __attribute__((ext_vector_type(2)));

static __device__ __forceinline__ f32x2 fma2(f32x2 w, float h, f32x2 a) {
  return __builtin_elementwise_fma(w, (f32x2){h, h}, a);
}

__global__ void gumbel_noise_kernel(const float4* __restrict__ u,
                                    float4* __restrict__ o, int n4) {
  int i = blockIdx.x * blockDim.x + threadIdx.x;
  int stride = gridDim.x * blockDim.x;
  for (; i < n4; i += stride) {
    float4 v = u[i];
    float4 r;
    r.x = -logf(-logf(v.x + 1e-20f) + 1e-20f);
    r.y = -logf(-logf(v.y + 1e-20f) + 1e-20f);
    r.z = -logf(-logf(v.z + 1e-20f) + 1e-20f);
    r.w = -logf(-logf(v.w + 1e-20f) + 1e-20f);
    o[i] = r;
  }
}

template <int PRE>
__global__ __launch_bounds__(64, 4) void gen_decoder_kernel(
    const float* __restrict__ h_n, const float* __restrict__ c_n,
    const float* __restrict__ noise, const float* __restrict__ gsrc,
    const float* __restrict__ W_init, const float* __restrict__ b_init,
    const float* __restrict__ W_ih, const float* __restrict__ W_hh,
    const float* __restrict__ b_ih, const float* __restrict__ b_hh,
    const float* __restrict__ W_head, const float* __restrict__ b_head,
    float* __restrict__ out, int B, int T)
{
  __shared__ f32x2 sTIG[8 * 32];   // [k][j] = {v(j,k),    v(64+j,k)}  (i,g rows)
  __shared__ f32x2 sTFO[8 * 32];   // [k][j] = {v(32+j,k), v(96+j,k)}  (f,o rows)
  __shared__ __align__(16) float sm_h[2 * 36];   // per-half h, stride 36
  __shared__ __align__(16) float smL[2][56];     // 8 steps x 7 logits
  __shared__ __align__(16) float smS[2][56];     // 8 steps x 7 samples

  const int l    = threadIdx.x;     // one wave per block
  const int half = l >> 5;          // batch half 0/1
  const int j    = l & 31;          // state slot
  const int b    = blockIdx.x * 2 + half;

  // fused W_ih/bias tables (wave-local, in-order: no barrier needed)
  // v(r,k) = b_ih[r] + b_hh[r] + (k<7 ? W_ih[r*7+k] : 0)  — same value/order
  for (int i = l; i < 8 * 32; i += 64) {
    int k = i >> 5, jj = i & 31;
    float vi = b_ih[jj]      + b_hh[jj]      + ((k < 7) ? W_ih[jj * 7 + k]        : 0.f);
    float vf = b_ih[32 + jj] + b_hh[32 + jj] + ((k < 7) ? W_ih[(32 + jj) * 7 + k] : 0.f);
    float vg = b_ih[64 + jj] + b_hh[64 + jj] + ((k < 7) ? W_ih[(64 + jj) * 7 + k] : 0.f);
    float vo = b_ih[96 + jj] + b_hh[96 + jj] + ((k < 7) ? W_ih[(96 + jj) * 7 + k] : 0.f);
    sTIG[i] = (f32x2){vi, vg};
    sTFO[i] = (f32x2){vf, vo};
  }

  // ---- h0 init (x dies before weight registers are allocated) ----
  {
    float x[Hh + NDd];
#pragma unroll
    for (int i = 0; i < 8; i++)
      ((float4*)x)[i] = *(const float4*)&h_n[(size_t)b * Hh + 4 * i];
    ((float4*)x)[8] = *(const float4*)&noise[(size_t)b * NDd];
    ((float4*)x)[9] = *(const float4*)&noise[(size_t)b * NDd + 4];
    float a = b_init[j];
    const float* wr = &W_init[j * (Hh + NDd)];
#pragma unroll
    for (int k = 0; k < Hh + NDd; k++) a = fmaf(wr[k], x[k], a);
    sm_h[half * 36 + j] = a;
  }
  float c = c_n[(size_t)b * Hh + j];

  // ---- recurrent weights: rows rA = l (i|f row j), rB = l+64 (g|o row j),
  //      packed {rA, rB} -> 64 VGPRs/lane, shared by both batches ----
  f32x2 wPK[32];
  {
    const float* WA = W_hh + (size_t)l * Hh;
    const float* WB = W_hh + (size_t)(l + 64) * Hh;
#pragma unroll
    for (int kc = 0; kc < 8; kc++) {
      float4 wa = *(const float4*)&WA[4 * kc];
      float4 wb = *(const float4*)&WB[4 * kc];
      wPK[4 * kc + 0] = (f32x2){wa.x, wb.x};
      wPK[4 * kc + 1] = (f32x2){wa.y, wb.y};
      wPK[4 * kc + 2] = (f32x2){wa.z, wb.z};
      wPK[4 * kc + 3] = (f32x2){wa.w, wb.w};
    }
  }
  const f32x2* tbl = half ? sTFO : sTIG;   // own rows' init table

  // head weights: within each half, lane 4p+q (p<7) holds W_head[p][q+4m]
  const int hp = (l & 31) >> 2;
  const int hq = l & 3;
  float whead[8];
  float bh = 0.f;
  if (hp < 7) {
#pragma unroll
    for (int m = 0; m < 8; m++) whead[m] = W_head[hp * Hh + hq + 4 * m];
    bh = b_head[hp];
  } else {
#pragma unroll
    for (int m = 0; m < 8; m++) whead[m] = 0.f;
  }

  const int r7 = l & 7;               // candidate index in 8-lane argmax group
  const int cpc = (r7 < 7) ? r7 : 6;
  const float* gL = gsrc + (size_t)b * Pp + cpc;
  const size_t strideT = (size_t)B * Pp;
  const size_t SOFF = (size_t)B * T * Pp;   // samples block offset (floats)

  int kA = 7, kB = 7;   // y0 = 0 -> bias-only column
  float* outL = out + (size_t)b * T * Pp;

  for (int t = 0; t < T; ++t) {
    // gumbel noise for this step (independent of recurrence -> issue early)
    float nv;
    if constexpr (PRE) {
      nv = gL[(size_t)t * strideT];
    } else {
      float uv = gL[(size_t)t * strideT];
      nv = -logf(-logf(uv + 1e-20f) + 1e-20f);   // exact same text
    }

    // packed gate chains for BOTH batches (k-ascending, bit-identical rows)
    f32x2 accA = tbl[(kA << 5) + j];
    f32x2 accB = tbl[(kB << 5) + j];
#pragma unroll
    for (int kc = 0; kc < 8; kc++) {
      float4 hvA = *(const float4*)&sm_h[4 * kc];        // batch A h (uniform)
      float4 hvB = *(const float4*)&sm_h[36 + 4 * kc];   // batch B h (uniform)
      accA = fma2(wPK[4 * kc + 0], hvA.x, accA);
      accB = fma2(wPK[4 * kc + 0], hvB.x, accB);
      accA = fma2(wPK[4 * kc + 1], hvA.y, accA);
      accB = fma2(wPK[4 * kc + 1], hvB.y, accB);
      accA = fma2(wPK[4 * kc + 2], hvA.z, accA);
      accB = fma2(wPK[4 * kc + 2], hvB.z, accB);
      accA = fma2(wPK[4 * kc + 3], hvA.w, accA);
      accB = fma2(wPK[4 * kc + 3], hvB.w, accB);
    }

    // exchange: lanes<32 assemble batch A's (i,f,g,o); lanes>=32 batch B's
    float xAx = __shfl_xor(accA.x, 32), xAy = __shfl_xor(accA.y, 32);
    float xBx = __shfl_xor(accB.x, 32), xBy = __shfl_xor(accB.y, 32);
    float i_pre = (l < 32) ? accA.x : xBx;
    float g_pre = (l < 32) ? accA.y : xBy;
    float f_pre = (l < 32) ? xAx : accB.x;
    float o_pre = (l < 32) ? xAy : accB.y;

    // cell (exact expression text of rounds 1-7); lane<32 -> A, lane>=32 -> B
    float ig = 1.f / (1.f + expf(-i_pre));
    float fg = 1.f / (1.f + expf(-f_pre));
    float gg = tanhf(g_pre);
    float og = 1.f / (1.f + expf(-o_pre));
    float cc = fg * c + ig * gg;
    c = cc;
    float hj = og * tanhf(cc);
    sm_h[half * 36 + j] = hj;   // half 0 writes A, half 1 writes B

    // head: lane 4p+q partial over m ascending, xor1/xor2 quad tree, + bias
    float lgp = 0.f;
    if (hp < 7) {
#pragma unroll
      for (int m = 0; m < 8; m++)
        lgp = fmaf(whead[m], sm_h[half * 36 + hq + 4 * m], lgp);
      lgp += __shfl_xor(lgp, 1);
      lgp += __shfl_xor(lgp, 2);
      lgp += bh;
    }

    // fan logit r7 of own half to this lane (lane 4*r7 of own half holds it)
    float Lr = __shfl(lgp, (l & 32) + 4 * cpc);

    // 8-lane lowest-index argmax butterfly (half-local groups)
    float bestv = (r7 < 7) ? (Lr + nv) : -__builtin_inff();
    int besti = r7;
#pragma unroll
    for (int mask = 1; mask <= 4; mask <<= 1) {
      float ov = __shfl_xor(bestv, mask);
      int   oi = __shfl_xor(besti, mask);
      if (ov > bestv || (ov == bestv && oi < besti)) { bestv = ov; besti = oi; }
    }
    kA = __shfl(besti, 0);
    kB = __shfl(besti, 32);
    int kme = (l < 32) ? kA : kB;

    // stage outputs (quad leaders p<7 of each half)
    if (hp < 7 && hq == 0) {
      int t8 = (t & 7) * Pp + hp;
      smL[half][t8] = lgp;
      smS[half][t8] = (kme == hp) ? 1.f : 0.f;
    }

    // flush every 8 steps: 14 float4 per batch half
    if ((t & 7) == 7) {
      int r = l & 31;
      if (r < 14) {
        size_t o = (size_t)(t - 7) * Pp + 4 * r;
        *(float4*)&outL[o]        = *(const float4*)&smL[half][4 * r];
        *(float4*)&outL[o + SOFF] = *(const float4*)&smS[half][4 * r];
      }
    } else if (t == T - 1) {
      int t0 = t & ~7;
      int cnt = (t - t0 + 1) * Pp;
      for (int i = l & 31; i < cnt; i += 32) {
        size_t o = (size_t)t0 * Pp + i;
        outL[o]        = smL[half][i];
        outL[o + SOFF] = smS[half][i];
      }
    }
  }
}

extern "C" void kernel_launch(void* const* d_in, const int* in_sizes, int n_in,
                              void* d_out, int out_size, void* d_ws, size_t ws_size,
                              hipStream_t stream) {
  const float* h_n     = (const float*)d_in[0];
  const float* c_n     = (const float*)d_in[1];
  const float* noise   = (const float*)d_in[2];
  const float* gumbel  = (const float*)d_in[3];
  const float* W_init  = (const float*)d_in[4];
  const float* b_init  = (const float*)d_in[5];
  const float* W_ih    = (const float*)d_in[6];
  const float* W_hh    = (const float*)d_in[7];
  const float* b_ih    = (const float*)d_in[8];
  const float* b_hh    = (const float*)d_in[9];
  const float* W_head  = (const float*)d_in[10];
  const float* b_head  = (const float*)d_in[11];

  int B = in_sizes[0] / Hh;                 // 32768
  int n = in_sizes[3];                      // T*B*P
  int T = n / (B * Pp);                     // 128
  size_t nbytes = (size_t)n * sizeof(float);
  bool pre = (ws_size >= nbytes) && (n % 4 == 0);

  if (pre) {
    gumbel_noise_kernel<<<2048, 256, 0, stream>>>(
        (const float4*)gumbel, (float4*)d_ws, n / 4);
    gen_decoder_kernel<1><<<dim3(B / 2), dim3(64), 0, stream>>>(
        h_n, c_n, noise, (const float*)d_ws, W_init, b_init, W_ih, W_hh,
        b_ih, b_hh, W_head, b_head, (float*)d_out, B, T);
  } else {
    gen_decoder_kernel<0><<<dim3(B / 2), dim3(64), 0, stream>>>(
        h_n, c_n, noise, gumbel, W_init, b_init, W_ih, W_hh,
        b_ih, b_hh, W_head, b_head, (float*)d_out, B, T);
  }
}